// Round 2
// baseline (2517.745 us; speedup 1.0000x reference)
//
#include <hip/hip_runtime.h>
#include <math.h>

#define BB 4
#define NN 32768
#define CC 512
#define MM 512
#define CAP 8192
#define KPT 32   // CAP / 256 threads

// ---- workspace layout (bytes) ----
#define OFF_G      0
#define OFF_MASK   (OFF_G + BB*NN*4)           // graspness f32
#define OFF_CNT    (OFF_MASK + BB*NN)          // mask u8
#define OFF_CIDX   (OFF_CNT + 256)             // cnt ints (padded)
#define OFF_CXYZD  (OFF_CIDX + BB*CAP*4)       // compacted orig indices (kept for debug/unused)
#define OFF_IDXSEL (OFF_CXYZD + BB*CAP*16)     // compacted float4 {x,y,z, idx_bits}
#define OFF_DSLOW  (OFF_IDXSEL + BB*MM*4)      // selected orig indices
// total = OFF_DSLOW + BB*NN*4 ~= 1.85 MB

// ---------------- kernel 1: scoring heads + mask ----------------
__global__ __launch_bounds__(256) void k_score(const float* __restrict__ feat,
                                               const float* __restrict__ Wobj,
                                               const float* __restrict__ bobj,
                                               const float* __restrict__ Wg,
                                               const float* __restrict__ bg,
                                               float* __restrict__ g_out,
                                               unsigned char* __restrict__ mask_out) {
    __shared__ float w0[CC], w1[CC], wg[CC];
    for (int c = threadIdx.x; c < CC; c += 256) {
        w0[c] = Wobj[c];
        w1[c] = Wobj[CC + c];
        wg[c] = Wg[c];
    }
    __syncthreads();
    int b = blockIdx.y;
    int n = blockIdx.x * 256 + threadIdx.x;
    const float* f = feat + (size_t)b * CC * NN + n;
    double a0 = 0.0, a1 = 0.0, ag = 0.0;
#pragma unroll 8
    for (int c = 0; c < CC; c++) {
        double fv = (double)f[(size_t)c * NN];
        a0 += fv * (double)w0[c];
        a1 += fv * (double)w1[c];
        ag += fv * (double)wg[c];
    }
    float o0 = (float)(a0 + (double)bobj[0]);
    float o1 = (float)(a1 + (double)bobj[1]);
    float g  = (float)(ag + (double)bg[0]);
    g_out[b * NN + n] = g;
    // argmax([o0,o1])==1 requires strict o1>o0 (argmax picks first max)
    mask_out[b * NN + n] = (o1 > o0 && g > 0.1f) ? 1 : 0;
}

// ---------------- kernel 2: stable compaction of masked points ----------------
__global__ __launch_bounds__(1024) void k_compact(const float* __restrict__ pc,
                                                  const unsigned char* __restrict__ mask,
                                                  int* __restrict__ cnt,
                                                  int* __restrict__ cidx,
                                                  float4* __restrict__ cxyzd) {
    int b = blockIdx.x, tid = threadIdx.x;
    int lane = tid & 63, wv = tid >> 6;
    __shared__ int wcnt[16], woff[16];
    __shared__ int base;
    if (tid == 0) base = 0;
    __syncthreads();
    for (int ch = 0; ch < NN / 1024; ch++) {
        int n = ch * 1024 + tid;
        bool m = mask[(size_t)b * NN + n] != 0;
        unsigned long long bal = __ballot(m);
        int before = __popcll(bal & ((1ull << lane) - 1ull));
        if (lane == 0) wcnt[wv] = __popcll(bal);
        __syncthreads();
        if (tid == 0) {
            int r = base;
            for (int w = 0; w < 16; w++) { woff[w] = r; r += wcnt[w]; }
            base = r;
        }
        __syncthreads();
        if (m) {
            int pos = woff[wv] + before;
            if (pos < CAP) {
                cidx[b * CAP + pos] = n;
                const float* p = pc + ((size_t)b * NN + n) * 3;
                // pack original index bits into .w so FPS needs no global reads
                cxyzd[b * CAP + pos] = make_float4(p[0], p[1], p[2], __int_as_float(n));
            }
        }
        __syncthreads();
    }
    if (tid == 0) cnt[b] = base;
}

// ---------------- DPP helpers (row_shr pair-argmax, VALU-latency) ----------------
template<int CTRL>
__device__ __forceinline__ void dpp_pair_max(float& v, int& p) {
    int svi = __builtin_amdgcn_update_dpp(__float_as_int(v), __float_as_int(v),
                                          CTRL, 0xF, 0xF, false);
    int sp  = __builtin_amdgcn_update_dpp(p, p, CTRL, 0xF, 0xF, false);
    float sv = __int_as_float(svi);
    if (sv > v || (sv == v && sp < p)) { v = sv; p = sp; }
}

// ---------------- kernel 3: FPS, points register-resident ----------------
__global__ __launch_bounds__(256, 1) void k_fps(const int* __restrict__ cnt,
                                                const float4* __restrict__ cxyzd_g,
                                                int* __restrict__ idxsel) {
    int b = blockIdx.x, tid = threadIdx.x;
    int wv = tid >> 6;
    int nc = cnt[b];
    if (nc == 0) {  // no graspable points: reference selects index 0 forever
        for (int i = tid; i < MM; i += 256) idxsel[b * MM + i] = 0;
        return;
    }
    if (nc > CAP) return;  // slow-path kernel handles this

    __shared__ float4 xyzc[CAP];      // 128 KiB: {x,y,z, orig_idx_bits}, read-only in loop
    __shared__ int4   red4[2][2];     // double-buffered 4x{val,idx} cross-wave slots

    float px[KPT], py[KPT], pz[KPT], pd[KPT];
    const float4* src = cxyzd_g + (size_t)b * CAP;
#pragma unroll
    for (int k = 0; k < KPT; k++) {
        int p = k * 256 + tid;
        bool valid = p < nc;
        float4 v = make_float4(0.f, 0.f, 0.f, 0.f);
        if (valid) v = src[p];
        px[k] = v.x; py[k] = v.y; pz[k] = v.z;
        pd[k] = valid ? __builtin_inff() : -__builtin_inff();
        if (valid) xyzc[p] = v;
    }
    __syncthreads();

    int last = 0;  // compacted index of first masked point
    for (int it = 0; it < MM; it++) {
        int buf = it & 1;
        float4 c4 = xyzc[last];                       // broadcast read
        if (tid == 0) idxsel[b * MM + it] = __float_as_int(c4.w);  // emit pre-update center

        float bv = -__builtin_inff();
        int bk = 0;
#pragma unroll
        for (int k = 0; k < KPT; k++) {
            // exact f32, no FMA contraction: ((dx*dx + dy*dy) + dz*dz)
            float dx = __fsub_rn(px[k], c4.x);
            float dy = __fsub_rn(py[k], c4.y);
            float dz = __fsub_rn(pz[k], c4.z);
            float d = __fadd_rn(__fadd_rn(__fmul_rn(dx, dx), __fmul_rn(dy, dy)),
                                __fmul_rn(dz, dz));
            float nd = fminf(pd[k], d);
            pd[k] = nd;
            if (nd > bv) { bv = nd; bk = k; }  // strict > keeps smallest slot
        }
        int bp = bk * 256 + tid;  // compacted index; monotone in (k, tid) order

        // wave64 pair-argmax: 4 DPP row_shr levels -> row winners at lanes 15/31/47/63
        dpp_pair_max<0x111>(bv, bp);  // row_shr:1
        dpp_pair_max<0x112>(bv, bp);  // row_shr:2
        dpp_pair_max<0x114>(bv, bp);  // row_shr:4
        dpp_pair_max<0x118>(bv, bp);  // row_shr:8
        int v15 = __builtin_amdgcn_readlane(__float_as_int(bv), 15);
        int p15 = __builtin_amdgcn_readlane(bp, 15);
        int v31 = __builtin_amdgcn_readlane(__float_as_int(bv), 31);
        int p31 = __builtin_amdgcn_readlane(bp, 31);
        int v47 = __builtin_amdgcn_readlane(__float_as_int(bv), 47);
        int p47 = __builtin_amdgcn_readlane(bp, 47);
        int v63 = __builtin_amdgcn_readlane(__float_as_int(bv), 63);
        int p63 = __builtin_amdgcn_readlane(bp, 63);
        float rv = __int_as_float(v15); int rp = p15;
        {
            float f;
            f = __int_as_float(v31); if (f > rv || (f == rv && p31 < rp)) { rv = f; rp = p31; }
            f = __int_as_float(v47); if (f > rv || (f == rv && p47 < rp)) { rv = f; rp = p47; }
            f = __int_as_float(v63); if (f > rv || (f == rv && p63 < rp)) { rv = f; rp = p63; }
        }
        if ((tid & 63) == 0)
            ((int2*)&red4[buf][0])[wv] = make_int2(__float_as_int(rv), rp);
        __syncthreads();

        int4 ra = red4[buf][0];
        int4 rb = red4[buf][1];
        float fv = __int_as_float(ra.x); int fp = ra.y;
        {
            float f;
            f = __int_as_float(ra.z); if (f > fv || (f == fv && ra.w < fp)) { fv = f; fp = ra.w; }
            f = __int_as_float(rb.x); if (f > fv || (f == fv && rb.y < fp)) { fv = f; fp = rb.y; }
            f = __int_as_float(rb.z); if (f > fv || (f == fv && rb.w < fp)) { fv = f; fp = rb.w; }
        }
        last = fp;
    }
}

// ---------------- kernel 3b: FPS slow path (cnt > CAP; global arrays) ----------------
__global__ __launch_bounds__(1024) void k_fps_slow(const float* __restrict__ pc,
                                                   const unsigned char* __restrict__ mask,
                                                   const int* __restrict__ cnt,
                                                   float* __restrict__ dist,
                                                   int* __restrict__ idxsel) {
    int b = blockIdx.x, tid = threadIdx.x;
    int lane = tid & 63, wv = tid >> 6;
    if (cnt[b] <= CAP) return;
    __shared__ float redv[16];
    __shared__ int   redp[16];
    __shared__ int   bc;
    int firstn = 0x7fffffff;
    for (int n = tid; n < NN; n += 1024) {
        bool m = mask[(size_t)b * NN + n] != 0;
        dist[(size_t)b * NN + n] = m ? __builtin_inff() : -__builtin_inff();
        if (m && firstn == 0x7fffffff) firstn = n;
    }
    for (int off = 32; off >= 1; off >>= 1) {
        int on = __shfl_xor(firstn, off, 64);
        if (on < firstn) firstn = on;
    }
    if (lane == 0) redp[wv] = firstn;
    __syncthreads();
    if (tid < 64) {
        int p2 = (lane < 16) ? redp[lane] : 0x7fffffff;
        for (int off = 8; off >= 1; off >>= 1) {
            int op = __shfl_xor(p2, off, 64);
            if (op < p2) p2 = op;
        }
        if (lane == 0) bc = p2;
    }
    __threadfence_block();
    __syncthreads();
    int last = bc;
    for (int it = 0; it < MM; it++) {
        float cx = pc[((size_t)b * NN + last) * 3 + 0];
        float cy = pc[((size_t)b * NN + last) * 3 + 1];
        float cz = pc[((size_t)b * NN + last) * 3 + 2];
        float bv = -__builtin_inff();
        int bp = 0x7fffffff;
        for (int n = tid; n < NN; n += 1024) {
            float x = pc[((size_t)b * NN + n) * 3 + 0];
            float y = pc[((size_t)b * NN + n) * 3 + 1];
            float z = pc[((size_t)b * NN + n) * 3 + 2];
            float dx = __fsub_rn(x, cx), dy = __fsub_rn(y, cy), dz = __fsub_rn(z, cz);
            float d = __fadd_rn(__fadd_rn(__fmul_rn(dx, dx), __fmul_rn(dy, dy)),
                                __fmul_rn(dz, dz));
            float od = dist[(size_t)b * NN + n];
            float nd = fminf(od, d);
            dist[(size_t)b * NN + n] = nd;
            if (nd > bv) { bv = nd; bp = n; }
        }
        for (int off = 32; off >= 1; off >>= 1) {
            float ov = __shfl_xor(bv, off, 64);
            int   op = __shfl_xor(bp, off, 64);
            if (ov > bv || (ov == bv && op < bp)) { bv = ov; bp = op; }
        }
        if (lane == 0) { redv[wv] = bv; redp[wv] = bp; }
        if (tid == 1023) idxsel[b * MM + it] = last;
        __threadfence_block();
        __syncthreads();
        if (tid < 64) {
            float v2 = (lane < 16) ? redv[lane] : -__builtin_inff();
            int   p2 = (lane < 16) ? redp[lane] : 0x7fffffff;
            for (int off = 8; off >= 1; off >>= 1) {
                float ov = __shfl_xor(v2, off, 64);
                int   op = __shfl_xor(p2, off, 64);
                if (ov > v2 || (ov == v2 && op < p2)) { v2 = ov; p2 = op; }
            }
            if (lane == 0) bc = p2;
        }
        __threadfence_block();
        __syncthreads();
        last = bc;
    }
}

// ---------------- kernel 4: gather + pack [B, 516, 512] ----------------
__global__ __launch_bounds__(256) void k_gather(const float* __restrict__ pc,
                                                const float* __restrict__ feat,
                                                const float* __restrict__ g,
                                                const int* __restrict__ idxsel,
                                                float* __restrict__ out) {
    int bc_ = blockIdx.x;
    int b = bc_ / 516;
    int ch = bc_ % 516;
    for (int m = threadIdx.x; m < MM; m += 256) {
        int n = idxsel[b * MM + m];
        float v;
        if (ch < 512) v = feat[((size_t)b * CC + ch) * NN + n];
        else if (ch < 515) v = pc[((size_t)b * NN + n) * 3 + (ch - 512)];
        else v = g[b * NN + n];
        out[((size_t)b * 516 + ch) * MM + m] = v;
    }
}

extern "C" void kernel_launch(void* const* d_in, const int* in_sizes, int n_in,
                              void* d_out, int out_size, void* d_ws, size_t ws_size,
                              hipStream_t stream) {
    const float* pc    = (const float*)d_in[0];  // [B,N,3]
    const float* feat  = (const float*)d_in[1];  // [B,C,N]
    const float* Wobj  = (const float*)d_in[2];  // [2,C]
    const float* bobj  = (const float*)d_in[3];  // [2]
    const float* Wg    = (const float*)d_in[4];  // [C]
    const float* bg    = (const float*)d_in[5];  // [1]
    float* out = (float*)d_out;

    char* ws = (char*)d_ws;
    float*         g_buf   = (float*)(ws + OFF_G);
    unsigned char* mask    = (unsigned char*)(ws + OFF_MASK);
    int*           cnt     = (int*)(ws + OFF_CNT);
    int*           cidx    = (int*)(ws + OFF_CIDX);
    float4*        cxyzd   = (float4*)(ws + OFF_CXYZD);
    int*           idxsel  = (int*)(ws + OFF_IDXSEL);
    float*         dslow   = (float*)(ws + OFF_DSLOW);

    k_score<<<dim3(NN / 256, BB), 256, 0, stream>>>(feat, Wobj, bobj, Wg, bg, g_buf, mask);
    k_compact<<<BB, 1024, 0, stream>>>(pc, mask, cnt, cidx, cxyzd);
    k_fps<<<BB, 256, 0, stream>>>(cnt, cxyzd, idxsel);
    k_fps_slow<<<BB, 1024, 0, stream>>>(pc, mask, cnt, dslow, idxsel);
    k_gather<<<BB * 516, 256, 0, stream>>>(pc, feat, g_buf, idxsel, out);
}

// Round 3
// 1142.677 us; speedup vs baseline: 2.2034x; 2.2034x over previous
//
#include <hip/hip_runtime.h>
#include <math.h>

#define BB 4
#define NN 32768
#define CC 512
#define MM 512
#define CAP 8192
#define TPB 1024
#define KPT (CAP / TPB)   // 8 slots per thread -> 32 VGPRs of arrays, no spill

// ---- workspace layout (bytes) ----
#define OFF_G      0
#define OFF_MASK   (OFF_G + BB*NN*4)           // graspness f32
#define OFF_CNT    (OFF_MASK + BB*NN)          // mask u8
#define OFF_CIDX   (OFF_CNT + 256)             // cnt ints (padded)
#define OFF_CXYZD  (OFF_CIDX + BB*CAP*4)       // compacted orig indices (unused by fast path)
#define OFF_IDXSEL (OFF_CXYZD + BB*CAP*16)     // compacted float4 {x,y,z, idx_bits}
#define OFF_DSLOW  (OFF_IDXSEL + BB*MM*4)      // slow-path dist array
// total = OFF_DSLOW + BB*NN*4 ~= 1.85 MB

// ---------------- kernel 1: scoring heads + mask ----------------
__global__ __launch_bounds__(256) void k_score(const float* __restrict__ feat,
                                               const float* __restrict__ Wobj,
                                               const float* __restrict__ bobj,
                                               const float* __restrict__ Wg,
                                               const float* __restrict__ bg,
                                               float* __restrict__ g_out,
                                               unsigned char* __restrict__ mask_out) {
    __shared__ float w0[CC], w1[CC], wg[CC];
    for (int c = threadIdx.x; c < CC; c += 256) {
        w0[c] = Wobj[c];
        w1[c] = Wobj[CC + c];
        wg[c] = Wg[c];
    }
    __syncthreads();
    int b = blockIdx.y;
    int n = blockIdx.x * 256 + threadIdx.x;
    const float* f = feat + (size_t)b * CC * NN + n;
    double a0 = 0.0, a1 = 0.0, ag = 0.0;
#pragma unroll 8
    for (int c = 0; c < CC; c++) {
        double fv = (double)f[(size_t)c * NN];
        a0 += fv * (double)w0[c];
        a1 += fv * (double)w1[c];
        ag += fv * (double)wg[c];
    }
    float o0 = (float)(a0 + (double)bobj[0]);
    float o1 = (float)(a1 + (double)bobj[1]);
    float g  = (float)(ag + (double)bg[0]);
    g_out[b * NN + n] = g;
    // argmax([o0,o1])==1 requires strict o1>o0 (argmax picks first max)
    mask_out[b * NN + n] = (o1 > o0 && g > 0.1f) ? 1 : 0;
}

// ---------------- kernel 2: stable compaction of masked points ----------------
__global__ __launch_bounds__(1024) void k_compact(const float* __restrict__ pc,
                                                  const unsigned char* __restrict__ mask,
                                                  int* __restrict__ cnt,
                                                  int* __restrict__ cidx,
                                                  float4* __restrict__ cxyzd) {
    int b = blockIdx.x, tid = threadIdx.x;
    int lane = tid & 63, wv = tid >> 6;
    __shared__ int wcnt[16], woff[16];
    __shared__ int base;
    if (tid == 0) base = 0;
    __syncthreads();
    for (int ch = 0; ch < NN / 1024; ch++) {
        int n = ch * 1024 + tid;
        bool m = mask[(size_t)b * NN + n] != 0;
        unsigned long long bal = __ballot(m);
        int before = __popcll(bal & ((1ull << lane) - 1ull));
        if (lane == 0) wcnt[wv] = __popcll(bal);
        __syncthreads();
        if (tid == 0) {
            int r = base;
            for (int w = 0; w < 16; w++) { woff[w] = r; r += wcnt[w]; }
            base = r;
        }
        __syncthreads();
        if (m) {
            int pos = woff[wv] + before;
            if (pos < CAP) {
                cidx[b * CAP + pos] = n;
                const float* p = pc + ((size_t)b * NN + n) * 3;
                // pack original index bits into .w so FPS needs no global reads
                cxyzd[b * CAP + pos] = make_float4(p[0], p[1], p[2], __int_as_float(n));
            }
        }
        __syncthreads();
    }
    if (tid == 0) cnt[b] = base;
}

// ---------------- DPP helpers (row_shr pair-argmax, VALU-latency) ----------------
template<int CTRL>
__device__ __forceinline__ void dpp_pair_max(float& v, int& p) {
    int svi = __builtin_amdgcn_update_dpp(__float_as_int(v), __float_as_int(v),
                                          CTRL, 0xF, 0xF, false);
    int sp  = __builtin_amdgcn_update_dpp(p, p, CTRL, 0xF, 0xF, false);
    float sv = __int_as_float(svi);
    if (sv > v || (sv == v && sp < p)) { v = sv; p = sp; }
}

// ---------------- kernel 3: FPS, points register-resident, KPT=8 ----------------
__global__ __launch_bounds__(TPB, 1) void k_fps(const int* __restrict__ cnt,
                                                const float4* __restrict__ cxyzd_g,
                                                int* __restrict__ idxsel) {
    int b = blockIdx.x, tid = threadIdx.x;
    int wv = tid >> 6;
    int nc = cnt[b];
    if (nc == 0) {  // no graspable points: reference selects index 0 forever
        for (int i = tid; i < MM; i += TPB) idxsel[b * MM + i] = 0;
        return;
    }
    if (nc > CAP) return;  // slow-path kernel handles this

    __shared__ float4 xyzc[CAP];      // 128 KiB: {x,y,z, orig_idx_bits}, read-only in loop
    __shared__ int2   red[2][16];     // double-buffered per-wave {val,idx} slots

    float px[KPT], py[KPT], pz[KPT], pd[KPT];
    const float4* src = cxyzd_g + (size_t)b * CAP;
#pragma unroll
    for (int k = 0; k < KPT; k++) {
        int p = k * TPB + tid;
        bool valid = p < nc;
        float4 v = make_float4(0.f, 0.f, 0.f, 0.f);
        if (valid) v = src[p];
        px[k] = v.x; py[k] = v.y; pz[k] = v.z;
        pd[k] = valid ? __builtin_inff() : -__builtin_inff();
        if (valid) xyzc[p] = v;
    }
    __syncthreads();

    int last = 0;  // compacted index of first masked point
    for (int it = 0; it < MM; it++) {
        int buf = it & 1;
        float4 c4 = xyzc[last];                       // broadcast LDS read
        if (tid == 0) idxsel[b * MM + it] = __float_as_int(c4.w);  // emit pre-update center

        float bv = -__builtin_inff();
        int bk = 0;
#pragma unroll
        for (int k = 0; k < KPT; k++) {
            // exact f32, no FMA contraction: ((dx*dx + dy*dy) + dz*dz)
            float dx = __fsub_rn(px[k], c4.x);
            float dy = __fsub_rn(py[k], c4.y);
            float dz = __fsub_rn(pz[k], c4.z);
            float d = __fadd_rn(__fadd_rn(__fmul_rn(dx, dx), __fmul_rn(dy, dy)),
                                __fmul_rn(dz, dz));
            float nd = fminf(pd[k], d);
            pd[k] = nd;
            if (nd > bv) { bv = nd; bk = k; }  // strict > keeps smallest slot k
        }
        int bp = bk * TPB + tid;  // compacted index

        // wave64 pair-argmax: 4 DPP row_shr levels -> row winners at lanes 15/31/47/63
        dpp_pair_max<0x111>(bv, bp);  // row_shr:1
        dpp_pair_max<0x112>(bv, bp);  // row_shr:2
        dpp_pair_max<0x114>(bv, bp);  // row_shr:4
        dpp_pair_max<0x118>(bv, bp);  // row_shr:8
        int v15 = __builtin_amdgcn_readlane(__float_as_int(bv), 15);
        int p15 = __builtin_amdgcn_readlane(bp, 15);
        int v31 = __builtin_amdgcn_readlane(__float_as_int(bv), 31);
        int p31 = __builtin_amdgcn_readlane(bp, 31);
        int v47 = __builtin_amdgcn_readlane(__float_as_int(bv), 47);
        int p47 = __builtin_amdgcn_readlane(bp, 47);
        int v63 = __builtin_amdgcn_readlane(__float_as_int(bv), 63);
        int p63 = __builtin_amdgcn_readlane(bp, 63);
        float rv = __int_as_float(v15); int rp = p15;
        {
            float f;
            f = __int_as_float(v31); if (f > rv || (f == rv && p31 < rp)) { rv = f; rp = p31; }
            f = __int_as_float(v47); if (f > rv || (f == rv && p47 < rp)) { rv = f; rp = p47; }
            f = __int_as_float(v63); if (f > rv || (f == rv && p63 < rp)) { rv = f; rp = p63; }
        }
        if ((tid & 63) == 0) red[buf][wv] = make_int2(__float_as_int(rv), rp);
        __syncthreads();

        // cross-wave combine: 16 entries, broadcast b128 reads, explicit idx tie-break
        int4 r0 = ((int4*)red[buf])[0];
        int4 r1 = ((int4*)red[buf])[1];
        int4 r2 = ((int4*)red[buf])[2];
        int4 r3 = ((int4*)red[buf])[3];
        int4 r4 = ((int4*)red[buf])[4];
        int4 r5 = ((int4*)red[buf])[5];
        int4 r6 = ((int4*)red[buf])[6];
        int4 r7 = ((int4*)red[buf])[7];
        float fv = __int_as_float(r0.x); int fp = r0.y;
        {
            float f;
            f = __int_as_float(r0.z); if (f > fv || (f == fv && r0.w < fp)) { fv = f; fp = r0.w; }
            f = __int_as_float(r1.x); if (f > fv || (f == fv && r1.y < fp)) { fv = f; fp = r1.y; }
            f = __int_as_float(r1.z); if (f > fv || (f == fv && r1.w < fp)) { fv = f; fp = r1.w; }
            f = __int_as_float(r2.x); if (f > fv || (f == fv && r2.y < fp)) { fv = f; fp = r2.y; }
            f = __int_as_float(r2.z); if (f > fv || (f == fv && r2.w < fp)) { fv = f; fp = r2.w; }
            f = __int_as_float(r3.x); if (f > fv || (f == fv && r3.y < fp)) { fv = f; fp = r3.y; }
            f = __int_as_float(r3.z); if (f > fv || (f == fv && r3.w < fp)) { fv = f; fp = r3.w; }
            f = __int_as_float(r4.x); if (f > fv || (f == fv && r4.y < fp)) { fv = f; fp = r4.y; }
            f = __int_as_float(r4.z); if (f > fv || (f == fv && r4.w < fp)) { fv = f; fp = r4.w; }
            f = __int_as_float(r5.x); if (f > fv || (f == fv && r5.y < fp)) { fv = f; fp = r5.y; }
            f = __int_as_float(r5.z); if (f > fv || (f == fv && r5.w < fp)) { fv = f; fp = r5.w; }
            f = __int_as_float(r6.x); if (f > fv || (f == fv && r6.y < fp)) { fv = f; fp = r6.y; }
            f = __int_as_float(r6.z); if (f > fv || (f == fv && r6.w < fp)) { fv = f; fp = r6.w; }
            f = __int_as_float(r7.x); if (f > fv || (f == fv && r7.y < fp)) { fv = f; fp = r7.y; }
            f = __int_as_float(r7.z); if (f > fv || (f == fv && r7.w < fp)) { fv = f; fp = r7.w; }
        }
        last = fp;
    }
}

// ---------------- kernel 3b: FPS slow path (cnt > CAP; global arrays) ----------------
__global__ __launch_bounds__(1024) void k_fps_slow(const float* __restrict__ pc,
                                                   const unsigned char* __restrict__ mask,
                                                   const int* __restrict__ cnt,
                                                   float* __restrict__ dist,
                                                   int* __restrict__ idxsel) {
    int b = blockIdx.x, tid = threadIdx.x;
    int lane = tid & 63, wv = tid >> 6;
    if (cnt[b] <= CAP) return;
    __shared__ float redv[16];
    __shared__ int   redp[16];
    __shared__ int   bc;
    int firstn = 0x7fffffff;
    for (int n = tid; n < NN; n += 1024) {
        bool m = mask[(size_t)b * NN + n] != 0;
        dist[(size_t)b * NN + n] = m ? __builtin_inff() : -__builtin_inff();
        if (m && firstn == 0x7fffffff) firstn = n;
    }
    for (int off = 32; off >= 1; off >>= 1) {
        int on = __shfl_xor(firstn, off, 64);
        if (on < firstn) firstn = on;
    }
    if (lane == 0) redp[wv] = firstn;
    __syncthreads();
    if (tid < 64) {
        int p2 = (lane < 16) ? redp[lane] : 0x7fffffff;
        for (int off = 8; off >= 1; off >>= 1) {
            int op = __shfl_xor(p2, off, 64);
            if (op < p2) p2 = op;
        }
        if (lane == 0) bc = p2;
    }
    __threadfence_block();
    __syncthreads();
    int last = bc;
    for (int it = 0; it < MM; it++) {
        float cx = pc[((size_t)b * NN + last) * 3 + 0];
        float cy = pc[((size_t)b * NN + last) * 3 + 1];
        float cz = pc[((size_t)b * NN + last) * 3 + 2];
        float bv = -__builtin_inff();
        int bp = 0x7fffffff;
        for (int n = tid; n < NN; n += 1024) {
            float x = pc[((size_t)b * NN + n) * 3 + 0];
            float y = pc[((size_t)b * NN + n) * 3 + 1];
            float z = pc[((size_t)b * NN + n) * 3 + 2];
            float dx = __fsub_rn(x, cx), dy = __fsub_rn(y, cy), dz = __fsub_rn(z, cz);
            float d = __fadd_rn(__fadd_rn(__fmul_rn(dx, dx), __fmul_rn(dy, dy)),
                                __fmul_rn(dz, dz));
            float od = dist[(size_t)b * NN + n];
            float nd = fminf(od, d);
            dist[(size_t)b * NN + n] = nd;
            if (nd > bv) { bv = nd; bp = n; }
        }
        for (int off = 32; off >= 1; off >>= 1) {
            float ov = __shfl_xor(bv, off, 64);
            int   op = __shfl_xor(bp, off, 64);
            if (ov > bv || (ov == bv && op < bp)) { bv = ov; bp = op; }
        }
        if (lane == 0) { redv[wv] = bv; redp[wv] = bp; }
        if (tid == 1023) idxsel[b * MM + it] = last;
        __threadfence_block();
        __syncthreads();
        if (tid < 64) {
            float v2 = (lane < 16) ? redv[lane] : -__builtin_inff();
            int   p2 = (lane < 16) ? redp[lane] : 0x7fffffff;
            for (int off = 8; off >= 1; off >>= 1) {
                float ov = __shfl_xor(v2, off, 64);
                int   op = __shfl_xor(p2, off, 64);
                if (ov > v2 || (ov == v2 && op < p2)) { v2 = ov; p2 = op; }
            }
            if (lane == 0) bc = p2;
        }
        __threadfence_block();
        __syncthreads();
        last = bc;
    }
}

// ---------------- kernel 4: gather + pack [B, 516, 512] ----------------
__global__ __launch_bounds__(256) void k_gather(const float* __restrict__ pc,
                                                const float* __restrict__ feat,
                                                const float* __restrict__ g,
                                                const int* __restrict__ idxsel,
                                                float* __restrict__ out) {
    int bc_ = blockIdx.x;
    int b = bc_ / 516;
    int ch = bc_ % 516;
    for (int m = threadIdx.x; m < MM; m += 256) {
        int n = idxsel[b * MM + m];
        float v;
        if (ch < 512) v = feat[((size_t)b * CC + ch) * NN + n];
        else if (ch < 515) v = pc[((size_t)b * NN + n) * 3 + (ch - 512)];
        else v = g[b * NN + n];
        out[((size_t)b * 516 + ch) * MM + m] = v;
    }
}

extern "C" void kernel_launch(void* const* d_in, const int* in_sizes, int n_in,
                              void* d_out, int out_size, void* d_ws, size_t ws_size,
                              hipStream_t stream) {
    const float* pc    = (const float*)d_in[0];  // [B,N,3]
    const float* feat  = (const float*)d_in[1];  // [B,C,N]
    const float* Wobj  = (const float*)d_in[2];  // [2,C]
    const float* bobj  = (const float*)d_in[3];  // [2]
    const float* Wg    = (const float*)d_in[4];  // [C]
    const float* bg    = (const float*)d_in[5];  // [1]
    float* out = (float*)d_out;

    char* ws = (char*)d_ws;
    float*         g_buf   = (float*)(ws + OFF_G);
    unsigned char* mask    = (unsigned char*)(ws + OFF_MASK);
    int*           cnt     = (int*)(ws + OFF_CNT);
    int*           cidx    = (int*)(ws + OFF_CIDX);
    float4*        cxyzd   = (float4*)(ws + OFF_CXYZD);
    int*           idxsel  = (int*)(ws + OFF_IDXSEL);
    float*         dslow   = (float*)(ws + OFF_DSLOW);

    k_score<<<dim3(NN / 256, BB), 256, 0, stream>>>(feat, Wobj, bobj, Wg, bg, g_buf, mask);
    k_compact<<<BB, 1024, 0, stream>>>(pc, mask, cnt, cidx, cxyzd);
    k_fps<<<BB, TPB, 0, stream>>>(cnt, cxyzd, idxsel);
    k_fps_slow<<<BB, 1024, 0, stream>>>(pc, mask, cnt, dslow, idxsel);
    k_gather<<<BB * 516, 256, 0, stream>>>(pc, feat, g_buf, idxsel, out);
}

// Round 4
// 740.431 us; speedup vs baseline: 3.4004x; 1.5433x over previous
//
#include <hip/hip_runtime.h>
#include <math.h>

#define BB 4
#define NN 32768
#define CC 512
#define MM 512
#define CAP 8192
#define TPB 512
#define KPT (CAP / TPB)    // 16 slots per thread (8 float2 pairs per axis)
#define NPAIR (KPT / 2)

typedef float f32x2 __attribute__((ext_vector_type(2)));

// ---- workspace layout (bytes) ----
#define OFF_G      0
#define OFF_MASK   (OFF_G + BB*NN*4)           // graspness f32
#define OFF_CNT    (OFF_MASK + BB*NN)          // mask u8
#define OFF_CIDX   (OFF_CNT + 256)             // cnt ints (padded)
#define OFF_CXYZD  (OFF_CIDX + BB*CAP*4)       // compacted orig indices (unused by fast path)
#define OFF_IDXSEL (OFF_CXYZD + BB*CAP*16)     // compacted float4 {x,y,z, idx_bits}
#define OFF_DSLOW  (OFF_IDXSEL + BB*MM*4)      // slow-path dist array
// total = OFF_DSLOW + BB*NN*4 ~= 1.85 MB

// ---------------- kernel 1: scoring heads + mask ----------------
__global__ __launch_bounds__(256) void k_score(const float* __restrict__ feat,
                                               const float* __restrict__ Wobj,
                                               const float* __restrict__ bobj,
                                               const float* __restrict__ Wg,
                                               const float* __restrict__ bg,
                                               float* __restrict__ g_out,
                                               unsigned char* __restrict__ mask_out) {
    __shared__ float w0[CC], w1[CC], wg[CC];
    for (int c = threadIdx.x; c < CC; c += 256) {
        w0[c] = Wobj[c];
        w1[c] = Wobj[CC + c];
        wg[c] = Wg[c];
    }
    __syncthreads();
    int b = blockIdx.y;
    int n = blockIdx.x * 256 + threadIdx.x;
    const float* f = feat + (size_t)b * CC * NN + n;
    double a0 = 0.0, a1 = 0.0, ag = 0.0;
#pragma unroll 8
    for (int c = 0; c < CC; c++) {
        double fv = (double)f[(size_t)c * NN];
        a0 += fv * (double)w0[c];
        a1 += fv * (double)w1[c];
        ag += fv * (double)wg[c];
    }
    float o0 = (float)(a0 + (double)bobj[0]);
    float o1 = (float)(a1 + (double)bobj[1]);
    float g  = (float)(ag + (double)bg[0]);
    g_out[b * NN + n] = g;
    // argmax([o0,o1])==1 requires strict o1>o0 (argmax picks first max)
    mask_out[b * NN + n] = (o1 > o0 && g > 0.1f) ? 1 : 0;
}

// ---------------- kernel 2: stable compaction of masked points ----------------
__global__ __launch_bounds__(1024) void k_compact(const float* __restrict__ pc,
                                                  const unsigned char* __restrict__ mask,
                                                  int* __restrict__ cnt,
                                                  int* __restrict__ cidx,
                                                  float4* __restrict__ cxyzd) {
    int b = blockIdx.x, tid = threadIdx.x;
    int lane = tid & 63, wv = tid >> 6;
    __shared__ int wcnt[16], woff[16];
    __shared__ int base;
    if (tid == 0) base = 0;
    __syncthreads();
    for (int ch = 0; ch < NN / 1024; ch++) {
        int n = ch * 1024 + tid;
        bool m = mask[(size_t)b * NN + n] != 0;
        unsigned long long bal = __ballot(m);
        int before = __popcll(bal & ((1ull << lane) - 1ull));
        if (lane == 0) wcnt[wv] = __popcll(bal);
        __syncthreads();
        if (tid == 0) {
            int r = base;
            for (int w = 0; w < 16; w++) { woff[w] = r; r += wcnt[w]; }
            base = r;
        }
        __syncthreads();
        if (m) {
            int pos = woff[wv] + before;
            if (pos < CAP) {
                cidx[b * CAP + pos] = n;
                const float* p = pc + ((size_t)b * NN + n) * 3;
                cxyzd[b * CAP + pos] = make_float4(p[0], p[1], p[2], __int_as_float(n));
            }
        }
        __syncthreads();
    }
    if (tid == 0) cnt[b] = base;
}

// ---------------- u64-key DPP pair-max (value desc, compacted idx asc) ----------------
template<int CTRL>
__device__ __forceinline__ void dpp_key_max(unsigned long long& key) {
    int lo = (int)(unsigned)key;
    int hi = (int)(unsigned)(key >> 32);
    int olo = __builtin_amdgcn_update_dpp(lo, lo, CTRL, 0xF, 0xF, false);
    int ohi = __builtin_amdgcn_update_dpp(hi, hi, CTRL, 0xF, 0xF, false);
    unsigned long long okey = ((unsigned long long)(unsigned)ohi << 32) | (unsigned)olo;
    if (okey > key) key = okey;
}

// ---------------- kernel 3: FPS, reg-resident, pk-f32 math, atomic key merge ----------------
__global__ __launch_bounds__(TPB, 1) void k_fps(const int* __restrict__ cnt,
                                                const float4* __restrict__ cxyzd_g,
                                                int* __restrict__ idxsel) {
    int b = blockIdx.x, tid = threadIdx.x;
    int nc = cnt[b];
    if (nc == 0) {  // no graspable points: reference selects index 0 forever
        for (int i = tid; i < MM; i += TPB) idxsel[b * MM + i] = 0;
        return;
    }
    if (nc > CAP) return;  // slow-path kernel handles this

    __shared__ float4 xyzc[CAP];              // 128 KiB: {x,y,z, orig_idx_bits}
    __shared__ unsigned long long sred[3];    // 3-slot rotating argmax key

    f32x2 px2[NPAIR], py2[NPAIR], pz2[NPAIR];
    float pd[KPT];
    const float4* src = cxyzd_g + (size_t)b * CAP;
#pragma unroll
    for (int j = 0; j < NPAIR; j++) {
        int p0 = (2 * j) * TPB + tid;
        int p1 = (2 * j + 1) * TPB + tid;
        bool v0 = p0 < nc, v1 = p1 < nc;
        float4 a = v0 ? src[p0] : make_float4(0.f, 0.f, 0.f, 0.f);
        float4 c = v1 ? src[p1] : make_float4(0.f, 0.f, 0.f, 0.f);
        px2[j] = (f32x2){a.x, c.x};
        py2[j] = (f32x2){a.y, c.y};
        pz2[j] = (f32x2){a.z, c.z};
        pd[2 * j]     = v0 ? __builtin_inff() : -__builtin_inff();
        pd[2 * j + 1] = v1 ? __builtin_inff() : -__builtin_inff();
        if (v0) xyzc[p0] = a;
        if (v1) xyzc[p1] = c;
    }
    if (tid == 0) { sred[0] = 0ull; sred[1] = 0ull; sred[2] = 0ull; }
    __syncthreads();

    int last = 0;   // compacted index of first masked point
    int s = 0;      // rotating slot
    for (int it = 0; it < MM; it++) {
        float4 c4 = xyzc[last];   // broadcast LDS read; .w = original index bits
        if (tid == 0) {
            idxsel[b * MM + it] = __float_as_int(c4.w);
            int zs = (s == 2) ? 0 : s + 1;     // safe: slot zs's readers synced 2 barriers ago
            sred[zs] = 0ull;
        }
        f32x2 ncx = {-c4.x, -c4.x};
        f32x2 ncy = {-c4.y, -c4.y};
        f32x2 ncz = {-c4.z, -c4.z};

        float bv = -__builtin_inff();
        int bk = 0;
#pragma unroll
        for (int j = 0; j < NPAIR; j++) {
            f32x2 dx, dy, dz, aa, bb, ss, cc2, d2;
            // exact f32 per half, no contraction: ((dx*dx + dy*dy) + dz*dz)
            asm("v_pk_add_f32 %0, %1, %2" : "=v"(dx) : "v"(px2[j]), "v"(ncx));
            asm("v_pk_add_f32 %0, %1, %2" : "=v"(dy) : "v"(py2[j]), "v"(ncy));
            asm("v_pk_add_f32 %0, %1, %2" : "=v"(dz) : "v"(pz2[j]), "v"(ncz));
            asm("v_pk_mul_f32 %0, %1, %1" : "=v"(aa) : "v"(dx));
            asm("v_pk_mul_f32 %0, %1, %1" : "=v"(bb) : "v"(dy));
            asm("v_pk_add_f32 %0, %1, %2" : "=v"(ss) : "v"(aa), "v"(bb));
            asm("v_pk_mul_f32 %0, %1, %1" : "=v"(cc2) : "v"(dz));
            asm("v_pk_add_f32 %0, %1, %2" : "=v"(d2) : "v"(ss), "v"(cc2));
            float nd0 = fminf(pd[2 * j], d2.x);
            pd[2 * j] = nd0;
            if (nd0 > bv) { bv = nd0; bk = 2 * j; }
            float nd1 = fminf(pd[2 * j + 1], d2.y);
            pd[2 * j + 1] = nd1;
            if (nd1 > bv) { bv = nd1; bk = 2 * j + 1; }
        }
        int bp = bk * TPB + tid;  // compacted index; k-order == compacted order

        // monotone f32->u32 map (handles -inf for all-invalid threads)
        unsigned u = (unsigned)__float_as_int(bv);
        unsigned mono = u ^ ((unsigned)(((int)u) >> 31) | 0x80000000u);
        // key: max key == max value, tie -> min compacted index
        unsigned long long key = ((unsigned long long)mono << 32) | (unsigned)(~bp);

        // wave-level pair-max over rows of 16 (lanes 15/31/47/63 hold row winners)
        dpp_key_max<0x111>(key);  // row_shr:1
        dpp_key_max<0x112>(key);  // row_shr:2
        dpp_key_max<0x114>(key);  // row_shr:4
        dpp_key_max<0x118>(key);  // row_shr:8
        if ((tid & 15) == 15)
            atomicMax(&sred[s], key);
        __syncthreads();

        unsigned long long w = sred[s];
        last = (int)(unsigned)(~(unsigned)w);
        s = (s == 2) ? 0 : s + 1;
    }
}

// ---------------- kernel 3b: FPS slow path (cnt > CAP; global arrays) ----------------
__global__ __launch_bounds__(1024) void k_fps_slow(const float* __restrict__ pc,
                                                   const unsigned char* __restrict__ mask,
                                                   const int* __restrict__ cnt,
                                                   float* __restrict__ dist,
                                                   int* __restrict__ idxsel) {
    int b = blockIdx.x, tid = threadIdx.x;
    int lane = tid & 63, wv = tid >> 6;
    if (cnt[b] <= CAP) return;
    __shared__ float redv[16];
    __shared__ int   redp[16];
    __shared__ int   bc;
    int firstn = 0x7fffffff;
    for (int n = tid; n < NN; n += 1024) {
        bool m = mask[(size_t)b * NN + n] != 0;
        dist[(size_t)b * NN + n] = m ? __builtin_inff() : -__builtin_inff();
        if (m && firstn == 0x7fffffff) firstn = n;
    }
    for (int off = 32; off >= 1; off >>= 1) {
        int on = __shfl_xor(firstn, off, 64);
        if (on < firstn) firstn = on;
    }
    if (lane == 0) redp[wv] = firstn;
    __syncthreads();
    if (tid < 64) {
        int p2 = (lane < 16) ? redp[lane] : 0x7fffffff;
        for (int off = 8; off >= 1; off >>= 1) {
            int op = __shfl_xor(p2, off, 64);
            if (op < p2) p2 = op;
        }
        if (lane == 0) bc = p2;
    }
    __threadfence_block();
    __syncthreads();
    int last = bc;
    for (int it = 0; it < MM; it++) {
        float cx = pc[((size_t)b * NN + last) * 3 + 0];
        float cy = pc[((size_t)b * NN + last) * 3 + 1];
        float cz = pc[((size_t)b * NN + last) * 3 + 2];
        float bv = -__builtin_inff();
        int bp = 0x7fffffff;
        for (int n = tid; n < NN; n += 1024) {
            float x = pc[((size_t)b * NN + n) * 3 + 0];
            float y = pc[((size_t)b * NN + n) * 3 + 1];
            float z = pc[((size_t)b * NN + n) * 3 + 2];
            float dx = __fsub_rn(x, cx), dy = __fsub_rn(y, cy), dz = __fsub_rn(z, cz);
            float d = __fadd_rn(__fadd_rn(__fmul_rn(dx, dx), __fmul_rn(dy, dy)),
                                __fmul_rn(dz, dz));
            float od = dist[(size_t)b * NN + n];
            float nd = fminf(od, d);
            dist[(size_t)b * NN + n] = nd;
            if (nd > bv) { bv = nd; bp = n; }
        }
        for (int off = 32; off >= 1; off >>= 1) {
            float ov = __shfl_xor(bv, off, 64);
            int   op = __shfl_xor(bp, off, 64);
            if (ov > bv || (ov == bv && op < bp)) { bv = ov; bp = op; }
        }
        if (lane == 0) { redv[wv] = bv; redp[wv] = bp; }
        if (tid == 1023) idxsel[b * MM + it] = last;
        __threadfence_block();
        __syncthreads();
        if (tid < 64) {
            float v2 = (lane < 16) ? redv[lane] : -__builtin_inff();
            int   p2 = (lane < 16) ? redp[lane] : 0x7fffffff;
            for (int off = 8; off >= 1; off >>= 1) {
                float ov = __shfl_xor(v2, off, 64);
                int   op = __shfl_xor(p2, off, 64);
                if (ov > v2 || (ov == v2 && op < p2)) { v2 = ov; p2 = op; }
            }
            if (lane == 0) bc = p2;
        }
        __threadfence_block();
        __syncthreads();
        last = bc;
    }
}

// ---------------- kernel 4: gather + pack [B, 516, 512] ----------------
__global__ __launch_bounds__(256) void k_gather(const float* __restrict__ pc,
                                                const float* __restrict__ feat,
                                                const float* __restrict__ g,
                                                const int* __restrict__ idxsel,
                                                float* __restrict__ out) {
    int bc_ = blockIdx.x;
    int b = bc_ / 516;
    int ch = bc_ % 516;
    for (int m = threadIdx.x; m < MM; m += 256) {
        int n = idxsel[b * MM + m];
        float v;
        if (ch < 512) v = feat[((size_t)b * CC + ch) * NN + n];
        else if (ch < 515) v = pc[((size_t)b * NN + n) * 3 + (ch - 512)];
        else v = g[b * NN + n];
        out[((size_t)b * 516 + ch) * MM + m] = v;
    }
}

extern "C" void kernel_launch(void* const* d_in, const int* in_sizes, int n_in,
                              void* d_out, int out_size, void* d_ws, size_t ws_size,
                              hipStream_t stream) {
    const float* pc    = (const float*)d_in[0];  // [B,N,3]
    const float* feat  = (const float*)d_in[1];  // [B,C,N]
    const float* Wobj  = (const float*)d_in[2];  // [2,C]
    const float* bobj  = (const float*)d_in[3];  // [2]
    const float* Wg    = (const float*)d_in[4];  // [C]
    const float* bg    = (const float*)d_in[5];  // [1]
    float* out = (float*)d_out;

    char* ws = (char*)d_ws;
    float*         g_buf   = (float*)(ws + OFF_G);
    unsigned char* mask    = (unsigned char*)(ws + OFF_MASK);
    int*           cnt     = (int*)(ws + OFF_CNT);
    int*           cidx    = (int*)(ws + OFF_CIDX);
    float4*        cxyzd   = (float4*)(ws + OFF_CXYZD);
    int*           idxsel  = (int*)(ws + OFF_IDXSEL);
    float*         dslow   = (float*)(ws + OFF_DSLOW);

    k_score<<<dim3(NN / 256, BB), 256, 0, stream>>>(feat, Wobj, bobj, Wg, bg, g_buf, mask);
    k_compact<<<BB, 1024, 0, stream>>>(pc, mask, cnt, cidx, cxyzd);
    k_fps<<<BB, TPB, 0, stream>>>(cnt, cxyzd, idxsel);
    k_fps_slow<<<BB, 1024, 0, stream>>>(pc, mask, cnt, dslow, idxsel);
    k_gather<<<BB * 516, 256, 0, stream>>>(pc, feat, g_buf, idxsel, out);
}

// Round 5
// 637.739 us; speedup vs baseline: 3.9479x; 1.1610x over previous
//
#include <hip/hip_runtime.h>
#include <math.h>

#define BB 4
#define NN 32768
#define CC 512
#define MM 512
#define CAP 8192
#define TPB 512
#define KPT (CAP / TPB)    // 16 slots per thread (8 float2 pairs per axis)
#define NPAIR (KPT / 2)

typedef float f32x2 __attribute__((ext_vector_type(2)));

// ---- workspace layout (bytes) ----
#define OFF_G      0
#define OFF_MASK   (OFF_G + BB*NN*4)           // graspness f32
#define OFF_CNT    (OFF_MASK + BB*NN)          // mask u8
#define OFF_CIDX   (OFF_CNT + 256)             // cnt ints (padded)
#define OFF_CXYZD  (OFF_CIDX + BB*CAP*4)       // compacted orig indices (unused by fast path)
#define OFF_IDXSEL (OFF_CXYZD + BB*CAP*16)     // compacted float4 {x,y,z, idx_bits}
#define OFF_DSLOW  (OFF_IDXSEL + BB*MM*4)      // slow-path dist array
// total = OFF_DSLOW + BB*NN*4 ~= 1.85 MB

// ---------------- kernel 1: scoring heads + mask ----------------
__global__ __launch_bounds__(256) void k_score(const float* __restrict__ feat,
                                               const float* __restrict__ Wobj,
                                               const float* __restrict__ bobj,
                                               const float* __restrict__ Wg,
                                               const float* __restrict__ bg,
                                               float* __restrict__ g_out,
                                               unsigned char* __restrict__ mask_out) {
    __shared__ float w0[CC], w1[CC], wg[CC];
    for (int c = threadIdx.x; c < CC; c += 256) {
        w0[c] = Wobj[c];
        w1[c] = Wobj[CC + c];
        wg[c] = Wg[c];
    }
    __syncthreads();
    int b = blockIdx.y;
    int n = blockIdx.x * 256 + threadIdx.x;
    const float* f = feat + (size_t)b * CC * NN + n;
    double a0 = 0.0, a1 = 0.0, ag = 0.0;
#pragma unroll 8
    for (int c = 0; c < CC; c++) {
        double fv = (double)f[(size_t)c * NN];
        a0 += fv * (double)w0[c];
        a1 += fv * (double)w1[c];
        ag += fv * (double)wg[c];
    }
    float o0 = (float)(a0 + (double)bobj[0]);
    float o1 = (float)(a1 + (double)bobj[1]);
    float g  = (float)(ag + (double)bg[0]);
    g_out[b * NN + n] = g;
    // argmax([o0,o1])==1 requires strict o1>o0 (argmax picks first max)
    mask_out[b * NN + n] = (o1 > o0 && g > 0.1f) ? 1 : 0;
}

// ---------------- kernel 2: stable compaction of masked points ----------------
__global__ __launch_bounds__(1024) void k_compact(const float* __restrict__ pc,
                                                  const unsigned char* __restrict__ mask,
                                                  int* __restrict__ cnt,
                                                  int* __restrict__ cidx,
                                                  float4* __restrict__ cxyzd) {
    int b = blockIdx.x, tid = threadIdx.x;
    int lane = tid & 63, wv = tid >> 6;
    __shared__ int wcnt[16], woff[16];
    __shared__ int base;
    if (tid == 0) base = 0;
    __syncthreads();
    for (int ch = 0; ch < NN / 1024; ch++) {
        int n = ch * 1024 + tid;
        bool m = mask[(size_t)b * NN + n] != 0;
        unsigned long long bal = __ballot(m);
        int before = __popcll(bal & ((1ull << lane) - 1ull));
        if (lane == 0) wcnt[wv] = __popcll(bal);
        __syncthreads();
        if (tid == 0) {
            int r = base;
            for (int w = 0; w < 16; w++) { woff[w] = r; r += wcnt[w]; }
            base = r;
        }
        __syncthreads();
        if (m) {
            int pos = woff[wv] + before;
            if (pos < CAP) {
                cidx[b * CAP + pos] = n;
                const float* p = pc + ((size_t)b * NN + n) * 3;
                cxyzd[b * CAP + pos] = make_float4(p[0], p[1], p[2], __int_as_float(n));
            }
        }
        __syncthreads();
    }
    if (tid == 0) cnt[b] = base;
}

// ---------------- u64-key DPP pair-max (value desc, compacted idx asc) ----------------
template<int CTRL, int RMASK>
__device__ __forceinline__ void dpp_key_max(unsigned long long& key) {
    int lo = (int)(unsigned)key;
    int hi = (int)(unsigned)(key >> 32);
    int olo = __builtin_amdgcn_update_dpp(lo, lo, CTRL, RMASK, 0xF, false);
    int ohi = __builtin_amdgcn_update_dpp(hi, hi, CTRL, RMASK, 0xF, false);
    unsigned long long okey = ((unsigned long long)(unsigned)ohi << 32) | (unsigned)olo;
    if (okey > key) key = okey;
}

// ---------------- kernel 3: FPS, reg-resident, fused pk-f32 asm, 64-lane DPP ----------------
__global__ __launch_bounds__(TPB, 1) void k_fps(const int* __restrict__ cnt,
                                                const float4* __restrict__ cxyzd_g,
                                                int* __restrict__ idxsel) {
    int b = blockIdx.x, tid = threadIdx.x;
    int nc = cnt[b];
    if (nc == 0) {  // no graspable points: reference selects index 0 forever
        for (int i = tid; i < MM; i += TPB) idxsel[b * MM + i] = 0;
        return;
    }
    if (nc > CAP) return;  // slow-path kernel handles this

    __shared__ float4 xyzc[CAP];              // 128 KiB: {x,y,z, orig_idx_bits}
    __shared__ unsigned long long sred[3];    // 3-slot rotating argmax key

    f32x2 px2[NPAIR], py2[NPAIR], pz2[NPAIR];
    float pd[KPT];
    const float4* src = cxyzd_g + (size_t)b * CAP;
#pragma unroll
    for (int j = 0; j < NPAIR; j++) {
        int p0 = (2 * j) * TPB + tid;
        int p1 = (2 * j + 1) * TPB + tid;
        bool v0 = p0 < nc, v1 = p1 < nc;
        float4 a = v0 ? src[p0] : make_float4(0.f, 0.f, 0.f, 0.f);
        float4 c = v1 ? src[p1] : make_float4(0.f, 0.f, 0.f, 0.f);
        px2[j] = (f32x2){a.x, c.x};
        py2[j] = (f32x2){a.y, c.y};
        pz2[j] = (f32x2){a.z, c.z};
        pd[2 * j]     = v0 ? __builtin_inff() : -__builtin_inff();
        pd[2 * j + 1] = v1 ? __builtin_inff() : -__builtin_inff();
        if (v0) xyzc[p0] = a;
        if (v1) xyzc[p1] = c;
    }
    if (tid == 0) { sred[0] = 0ull; sred[1] = 0ull; sred[2] = 0ull; }
    __syncthreads();

    unsigned ntid = ~(unsigned)tid;   // for keylo = ~(bk*TPB+tid) = ntid - (bk<<9)
    int last = 0;   // compacted index of first masked point
    int s = 0;      // rotating slot
    for (int it = 0; it < MM; it++) {
        float4 c4 = xyzc[last];   // broadcast LDS read; .w = original index bits
        if (tid == 0) {
            idxsel[b * MM + it] = __float_as_int(c4.w);
            int zs = (s == 2) ? 0 : s + 1;     // safe: slot zs's readers synced 2 barriers ago
            sred[zs] = 0ull;
        }
        f32x2 ncx = {-c4.x, -c4.x};
        f32x2 ncy = {-c4.y, -c4.y};
        f32x2 ncz = {-c4.z, -c4.z};

        float bv = -__builtin_inff();
        int bk = 0;
#pragma unroll
        for (int j = 0; j < NPAIR; j++) {
            f32x2 d2, t;
            // exact f32 per half, no contraction, fused block (no inter-op movs):
            // dx=px-cx; dy=py-cy; s=dx*dx+dy*dy; dz=pz-cz; d2=s+dz*dz
            asm("v_pk_add_f32 %0, %2, %4\n\t"
                "v_pk_add_f32 %1, %3, %5\n\t"
                "v_pk_mul_f32 %0, %0, %0\n\t"
                "v_pk_mul_f32 %1, %1, %1\n\t"
                "v_pk_add_f32 %0, %0, %1\n\t"
                "v_pk_add_f32 %1, %6, %7\n\t"
                "v_pk_mul_f32 %1, %1, %1\n\t"
                "v_pk_add_f32 %0, %0, %1"
                : "=&v"(d2), "=&v"(t)
                : "v"(px2[j]), "v"(py2[j]), "v"(ncx), "v"(ncy), "v"(pz2[j]), "v"(ncz));
            float nd0 = fminf(pd[2 * j], d2.x);
            pd[2 * j] = nd0;
            if (nd0 > bv) { bv = nd0; bk = 2 * j; }
            float nd1 = fminf(pd[2 * j + 1], d2.y);
            pd[2 * j + 1] = nd1;
            if (nd1 > bv) { bv = nd1; bk = 2 * j + 1; }
        }

        // monotone f32->u32 map (handles -inf for all-invalid threads)
        unsigned u = (unsigned)__float_as_int(bv);
        unsigned mono = u ^ ((unsigned)(((int)u) >> 31) | 0x80000000u);
        unsigned keylo = ntid - ((unsigned)bk << 9);   // == ~(bk*TPB+tid), TPB=512
        unsigned long long key = ((unsigned long long)mono << 32) | keylo;

        // full 64-lane DPP argmax: 4 row_shr + row_bcast15 + row_bcast31 -> lane 63
        dpp_key_max<0x111, 0xF>(key);  // row_shr:1
        dpp_key_max<0x112, 0xF>(key);  // row_shr:2
        dpp_key_max<0x114, 0xF>(key);  // row_shr:4
        dpp_key_max<0x118, 0xF>(key);  // row_shr:8
        dpp_key_max<0x142, 0xA>(key);  // row_bcast:15 -> rows 1,3
        dpp_key_max<0x143, 0xC>(key);  // row_bcast:31 -> rows 2,3
        if ((tid & 63) == 63)
            atomicMax(&sred[s], key);
        __syncthreads();

        unsigned long long w = sred[s];
        last = (int)(~(unsigned)w);
        s = (s == 2) ? 0 : s + 1;
    }
}

// ---------------- kernel 3b: FPS slow path (cnt > CAP; global arrays) ----------------
__global__ __launch_bounds__(1024) void k_fps_slow(const float* __restrict__ pc,
                                                   const unsigned char* __restrict__ mask,
                                                   const int* __restrict__ cnt,
                                                   float* __restrict__ dist,
                                                   int* __restrict__ idxsel) {
    int b = blockIdx.x, tid = threadIdx.x;
    int lane = tid & 63, wv = tid >> 6;
    if (cnt[b] <= CAP) return;
    __shared__ float redv[16];
    __shared__ int   redp[16];
    __shared__ int   bc;
    int firstn = 0x7fffffff;
    for (int n = tid; n < NN; n += 1024) {
        bool m = mask[(size_t)b * NN + n] != 0;
        dist[(size_t)b * NN + n] = m ? __builtin_inff() : -__builtin_inff();
        if (m && firstn == 0x7fffffff) firstn = n;
    }
    for (int off = 32; off >= 1; off >>= 1) {
        int on = __shfl_xor(firstn, off, 64);
        if (on < firstn) firstn = on;
    }
    if (lane == 0) redp[wv] = firstn;
    __syncthreads();
    if (tid < 64) {
        int p2 = (lane < 16) ? redp[lane] : 0x7fffffff;
        for (int off = 8; off >= 1; off >>= 1) {
            int op = __shfl_xor(p2, off, 64);
            if (op < p2) p2 = op;
        }
        if (lane == 0) bc = p2;
    }
    __threadfence_block();
    __syncthreads();
    int last = bc;
    for (int it = 0; it < MM; it++) {
        float cx = pc[((size_t)b * NN + last) * 3 + 0];
        float cy = pc[((size_t)b * NN + last) * 3 + 1];
        float cz = pc[((size_t)b * NN + last) * 3 + 2];
        float bv = -__builtin_inff();
        int bp = 0x7fffffff;
        for (int n = tid; n < NN; n += 1024) {
            float x = pc[((size_t)b * NN + n) * 3 + 0];
            float y = pc[((size_t)b * NN + n) * 3 + 1];
            float z = pc[((size_t)b * NN + n) * 3 + 2];
            float dx = __fsub_rn(x, cx), dy = __fsub_rn(y, cy), dz = __fsub_rn(z, cz);
            float d = __fadd_rn(__fadd_rn(__fmul_rn(dx, dx), __fmul_rn(dy, dy)),
                                __fmul_rn(dz, dz));
            float od = dist[(size_t)b * NN + n];
            float nd = fminf(od, d);
            dist[(size_t)b * NN + n] = nd;
            if (nd > bv) { bv = nd; bp = n; }
        }
        for (int off = 32; off >= 1; off >>= 1) {
            float ov = __shfl_xor(bv, off, 64);
            int   op = __shfl_xor(bp, off, 64);
            if (ov > bv || (ov == bv && op < bp)) { bv = ov; bp = op; }
        }
        if (lane == 0) { redv[wv] = bv; redp[wv] = bp; }
        if (tid == 1023) idxsel[b * MM + it] = last;
        __threadfence_block();
        __syncthreads();
        if (tid < 64) {
            float v2 = (lane < 16) ? redv[lane] : -__builtin_inff();
            int   p2 = (lane < 16) ? redp[lane] : 0x7fffffff;
            for (int off = 8; off >= 1; off >>= 1) {
                float ov = __shfl_xor(v2, off, 64);
                int   op = __shfl_xor(p2, off, 64);
                if (ov > v2 || (ov == v2 && op < p2)) { v2 = ov; p2 = op; }
            }
            if (lane == 0) bc = p2;
        }
        __threadfence_block();
        __syncthreads();
        last = bc;
    }
}

// ---------------- kernel 4: gather + pack [B, 516, 512] ----------------
__global__ __launch_bounds__(256) void k_gather(const float* __restrict__ pc,
                                                const float* __restrict__ feat,
                                                const float* __restrict__ g,
                                                const int* __restrict__ idxsel,
                                                float* __restrict__ out) {
    int bc_ = blockIdx.x;
    int b = bc_ / 516;
    int ch = bc_ % 516;
    for (int m = threadIdx.x; m < MM; m += 256) {
        int n = idxsel[b * MM + m];
        float v;
        if (ch < 512) v = feat[((size_t)b * CC + ch) * NN + n];
        else if (ch < 515) v = pc[((size_t)b * NN + n) * 3 + (ch - 512)];
        else v = g[b * NN + n];
        out[((size_t)b * 516 + ch) * MM + m] = v;
    }
}

extern "C" void kernel_launch(void* const* d_in, const int* in_sizes, int n_in,
                              void* d_out, int out_size, void* d_ws, size_t ws_size,
                              hipStream_t stream) {
    const float* pc    = (const float*)d_in[0];  // [B,N,3]
    const float* feat  = (const float*)d_in[1];  // [B,C,N]
    const float* Wobj  = (const float*)d_in[2];  // [2,C]
    const float* bobj  = (const float*)d_in[3];  // [2]
    const float* Wg    = (const float*)d_in[4];  // [C]
    const float* bg    = (const float*)d_in[5];  // [1]
    float* out = (float*)d_out;

    char* ws = (char*)d_ws;
    float*         g_buf   = (float*)(ws + OFF_G);
    unsigned char* mask    = (unsigned char*)(ws + OFF_MASK);
    int*           cnt     = (int*)(ws + OFF_CNT);
    int*           cidx    = (int*)(ws + OFF_CIDX);
    float4*        cxyzd   = (float4*)(ws + OFF_CXYZD);
    int*           idxsel  = (int*)(ws + OFF_IDXSEL);
    float*         dslow   = (float*)(ws + OFF_DSLOW);

    k_score<<<dim3(NN / 256, BB), 256, 0, stream>>>(feat, Wobj, bobj, Wg, bg, g_buf, mask);
    k_compact<<<BB, 1024, 0, stream>>>(pc, mask, cnt, cidx, cxyzd);
    k_fps<<<BB, TPB, 0, stream>>>(cnt, cxyzd, idxsel);
    k_fps_slow<<<BB, 1024, 0, stream>>>(pc, mask, cnt, dslow, idxsel);
    k_gather<<<BB * 516, 256, 0, stream>>>(pc, feat, g_buf, idxsel, out);
}